// Round 1
// baseline (307.428 us; speedup 1.0000x reference)
//
#include <hip/hip_runtime.h>
#include <stdint.h>

typedef unsigned short u16;
typedef __attribute__((ext_vector_type(8))) short short8;
typedef __attribute__((ext_vector_type(4))) float f32x4;

typedef __attribute__((address_space(1))) void as1_void;
typedef __attribute__((address_space(3))) void as3_void;

__device__ inline u16 f2bf(float x) {
  uint32_t u = __float_as_uint(x);
  return (u16)((u + 0x7fffu + ((u >> 16) & 1u)) >> 16);
}

__device__ inline void gload16(const void* g, void* l) {
  __builtin_amdgcn_global_load_lds((as1_void*)g, (as3_void*)l, 16, 0, 0);
}

// ---------------- f32 -> bf16 conversion (vectorized) ----------------
__global__ __launch_bounds__(256) void cvt_bf16_kernel(const float* __restrict__ in,
                                                       u16* __restrict__ out, int n4) {
  int i = blockIdx.x * 256 + threadIdx.x;
  if (i >= n4) return;
  float4 v = ((const float4*)in)[i];
  ushort4 o;
  o.x = f2bf(v.x); o.y = f2bf(v.y); o.z = f2bf(v.z); o.w = f2bf(v.w);
  ((ushort4*)out)[i] = o;
}

// ---------------- GEMM: C[m,n] = sum_k A[m,k]*W[n,k] + bias[n] ----------------
// M=8192, N=512, K=512. Tile 128x128, 4 waves (2x2), BK=32.
// MODE 0: bf16 out at [(b*8+h)*4096+s]*64+d   (Q/K head layout)
// MODE 1: bf16 out at [(b*8+h)*64+d]*4096+s   (V transposed)
// MODE 2: f32  out at m*512+n                  (final projection)
template <int MODE>
__global__ __launch_bounds__(256) void gemm_bt(const u16* __restrict__ A,
                                               const u16* __restrict__ W,
                                               const float* __restrict__ bias,
                                               void* __restrict__ Cout) {
  __shared__ u16 Al[128 * 32];
  __shared__ u16 Wl[128 * 32];
  const int tid = threadIdx.x;
  const int lane = tid & 63;
  const int wv = tid >> 6;
  const int c = lane & 15;
  const int g = lane >> 4;
  const int wr = wv >> 1, wc = wv & 1;
  const int m0 = blockIdx.x * 128;
  const int n0 = blockIdx.y * 128;

  f32x4 acc[4][4];
#pragma unroll
  for (int i = 0; i < 4; i++)
#pragma unroll
    for (int j = 0; j < 4; j++) acc[i][j] = (f32x4){0.f, 0.f, 0.f, 0.f};

  for (int kk = 0; kk < 512; kk += 32) {
    __syncthreads();
    {
      // stage A and W tiles: 512 chunks of 16B each; 2 chunks per thread per tile
      int t0 = tid;
      int r0 = t0 >> 2, c0 = t0 & 3;
      gload16(A + (size_t)(m0 + r0) * 512 + kk + c0 * 8, (char*)Al + (size_t)(wv * 64) * 16);
      gload16(W + (size_t)(n0 + r0) * 512 + kk + c0 * 8, (char*)Wl + (size_t)(wv * 64) * 16);
      int t1 = 256 + tid;
      int r1 = t1 >> 2, c1 = t1 & 3;
      gload16(A + (size_t)(m0 + r1) * 512 + kk + c1 * 8, (char*)Al + (size_t)(256 + wv * 64) * 16);
      gload16(W + (size_t)(n0 + r1) * 512 + kk + c1 * 8, (char*)Wl + (size_t)(256 + wv * 64) * 16);
    }
    __syncthreads();

    short8 af[4], wf[4];
#pragma unroll
    for (int ai = 0; ai < 4; ai++)
      af[ai] = *(const short8*)&Al[(wr * 64 + ai * 16 + c) * 32 + g * 8];
#pragma unroll
    for (int bj = 0; bj < 4; bj++)
      wf[bj] = *(const short8*)&Wl[(wc * 64 + bj * 16 + c) * 32 + g * 8];
#pragma unroll
    for (int ai = 0; ai < 4; ai++)
#pragma unroll
      for (int bj = 0; bj < 4; bj++)
        acc[ai][bj] = __builtin_amdgcn_mfma_f32_16x16x32_bf16(af[ai], wf[bj], acc[ai][bj], 0, 0, 0);
  }

  // epilogue: C/D layout col=lane&15, row=(lane>>4)*4+reg
#pragma unroll
  for (int ai = 0; ai < 4; ai++)
#pragma unroll
    for (int bj = 0; bj < 4; bj++)
#pragma unroll
      for (int r = 0; r < 4; r++) {
        int m = m0 + wr * 64 + ai * 16 + g * 4 + r;
        int n = n0 + wc * 64 + bj * 16 + c;
        float v = acc[ai][bj][r] + bias[n];
        if (MODE == 2) {
          ((float*)Cout)[(size_t)m * 512 + n] = v;
        } else {
          int b = m >> 12, s = m & 4095;
          int h = n >> 6, d = n & 63;
          size_t idx;
          if (MODE == 0)
            idx = ((size_t)(b * 8 + h) * 4096 + s) * 64 + d;
          else
            idx = ((size_t)(b * 8 + h) * 64 + d) * 4096 + s;
          ((u16*)Cout)[idx] = f2bf(v);
        }
      }
}

// ---------------- Flash attention ----------------
// Grid: 16 bh * 32 qtiles. Block 256 thr (4 waves), each wave owns 32 q rows.
// KV tiles of 64. K in LDS [64][72] (row=kv, col=d), V^T in LDS [64][72] (row=d, col=kv).
__global__ __launch_bounds__(256) void attn_kernel(const u16* __restrict__ Qh,
                                                   const u16* __restrict__ Kh,
                                                   const u16* __restrict__ Vt,
                                                   u16* __restrict__ Oa) {
  __shared__ u16 Kl[64][72];
  __shared__ u16 Vl[64][72];
  __shared__ u16 Pl[4][32][72];
  const int tid = threadIdx.x;
  const int lane = tid & 63;
  const int w = tid >> 6;
  const int c = lane & 15;
  const int g = lane >> 4;
  const int bh = blockIdx.x >> 5;
  const int qt = blockIdx.x & 31;
  const int q0 = qt * 128 + w * 32;
  const u16* Qb = Qh + (size_t)bh * 4096 * 64;
  const u16* Kb = Kh + (size_t)bh * 4096 * 64;
  const u16* Vb = Vt + (size_t)bh * 64 * 4096;

  // Q fragments held in registers for the whole kernel (A-layout: row=lane&15, k contiguous 8)
  short8 qf[2][2];
#pragma unroll
  for (int rb = 0; rb < 2; rb++)
#pragma unroll
    for (int ks = 0; ks < 2; ks++)
      qf[rb][ks] = *(const short8*)(Qb + (size_t)(q0 + rb * 16 + c) * 64 + ks * 32 + g * 8);

  f32x4 accO[2][4];
  float mr[2][4], lr[2][4];
#pragma unroll
  for (int rb = 0; rb < 2; rb++) {
#pragma unroll
    for (int cb = 0; cb < 4; cb++) accO[rb][cb] = (f32x4){0.f, 0.f, 0.f, 0.f};
#pragma unroll
    for (int r = 0; r < 4; r++) { mr[rb][r] = -1e30f; lr[rb][r] = 0.f; }
  }

  for (int kv0 = 0; kv0 < 4096; kv0 += 64) {
    __syncthreads();
    // stage K tile and V^T tile (each 64x64 bf16 = 512 x 16B chunks; 2 each per thread)
    {
      int t0 = tid;
      int r0 = t0 >> 3, c80 = t0 & 7;
      *(int4*)&Kl[r0][c80 * 8] = *(const int4*)(Kb + (size_t)(kv0 + r0) * 64 + c80 * 8);
      *(int4*)&Vl[r0][c80 * 8] = *(const int4*)(Vb + (size_t)r0 * 4096 + kv0 + c80 * 8);
      int t1 = 256 + tid;
      int r1 = t1 >> 3, c81 = t1 & 7;
      *(int4*)&Kl[r1][c81 * 8] = *(const int4*)(Kb + (size_t)(kv0 + r1) * 64 + c81 * 8);
      *(int4*)&Vl[r1][c81 * 8] = *(const int4*)(Vb + (size_t)r1 * 4096 + kv0 + c81 * 8);
    }
    __syncthreads();

    // S = Q * K^T  (scores for 32 q-rows x 64 kv)
    f32x4 accS[2][4];
#pragma unroll
    for (int rb = 0; rb < 2; rb++)
#pragma unroll
      for (int cb = 0; cb < 4; cb++) accS[rb][cb] = (f32x4){0.f, 0.f, 0.f, 0.f};
#pragma unroll
    for (int cb = 0; cb < 4; cb++)
#pragma unroll
      for (int ks = 0; ks < 2; ks++) {
        short8 kf = *(const short8*)&Kl[cb * 16 + c][ks * 32 + g * 8];
        accS[0][cb] = __builtin_amdgcn_mfma_f32_16x16x32_bf16(qf[0][ks], kf, accS[0][cb], 0, 0, 0);
        accS[1][cb] = __builtin_amdgcn_mfma_f32_16x16x32_bf16(qf[1][ks], kf, accS[1][cb], 0, 0, 0);
      }
    // scale by 1/sqrt(64)
#pragma unroll
    for (int rb = 0; rb < 2; rb++)
#pragma unroll
      for (int cb = 0; cb < 4; cb++)
#pragma unroll
        for (int r = 0; r < 4; r++) accS[rb][cb][r] *= 0.125f;

    // online softmax (row = lane>>4 *4 + r in C-layout; reduce across lanes 0..15)
#pragma unroll
    for (int rb = 0; rb < 2; rb++)
#pragma unroll
      for (int r = 0; r < 4; r++) {
        float tm = fmaxf(fmaxf(accS[rb][0][r], accS[rb][1][r]),
                         fmaxf(accS[rb][2][r], accS[rb][3][r]));
#pragma unroll
        for (int msk = 1; msk < 16; msk <<= 1) tm = fmaxf(tm, __shfl_xor(tm, msk));
        float mnew = fmaxf(mr[rb][r], tm);
        float corr = __expf(mr[rb][r] - mnew);
        float rs = 0.f;
#pragma unroll
        for (int cb = 0; cb < 4; cb++) {
          float p = __expf(accS[rb][cb][r] - mnew);
          accS[rb][cb][r] = p;
          rs += p;
        }
#pragma unroll
        for (int msk = 1; msk < 16; msk <<= 1) rs += __shfl_xor(rs, msk);
        lr[rb][r] = lr[rb][r] * corr + rs;
        mr[rb][r] = mnew;
#pragma unroll
        for (int cb = 0; cb < 4; cb++) accO[rb][cb][r] *= corr;
      }

    // P (C-layout) -> per-wave LDS -> re-read in A-layout
#pragma unroll
    for (int rb = 0; rb < 2; rb++)
#pragma unroll
      for (int cb = 0; cb < 4; cb++)
#pragma unroll
        for (int r = 0; r < 4; r++)
          Pl[w][rb * 16 + g * 4 + r][cb * 16 + c] = f2bf(accS[rb][cb][r]);
    asm volatile("" ::: "memory");  // keep ds_writes before ds_reads; DS pipe is in-order per wave

    // O += P * V
#pragma unroll
    for (int ks2 = 0; ks2 < 2; ks2++) {
      short8 pf0 = *(const short8*)&Pl[w][c][ks2 * 32 + g * 8];
      short8 pf1 = *(const short8*)&Pl[w][16 + c][ks2 * 32 + g * 8];
#pragma unroll
      for (int cb = 0; cb < 4; cb++) {
        short8 vf = *(const short8*)&Vl[cb * 16 + c][ks2 * 32 + g * 8];
        accO[0][cb] = __builtin_amdgcn_mfma_f32_16x16x32_bf16(pf0, vf, accO[0][cb], 0, 0, 0);
        accO[1][cb] = __builtin_amdgcn_mfma_f32_16x16x32_bf16(pf1, vf, accO[1][cb], 0, 0, 0);
      }
    }
  }

  // epilogue: normalize by row sum, write [b][s][h*64+d] bf16
  const int b = bh >> 3, h = bh & 7;
#pragma unroll
  for (int rb = 0; rb < 2; rb++)
#pragma unroll
    for (int cb = 0; cb < 4; cb++)
#pragma unroll
      for (int r = 0; r < 4; r++) {
        int sg = q0 + rb * 16 + g * 4 + r;
        int col = h * 64 + cb * 16 + c;
        float v = accO[rb][cb][r] / lr[rb][r];
        Oa[(size_t)(b * 4096 + sg) * 512 + col] = f2bf(v);
      }
}

// ---------------- host launch ----------------
extern "C" void kernel_launch(void* const* d_in, const int* in_sizes, int n_in,
                              void* d_out, int out_size, void* d_ws, size_t ws_size,
                              hipStream_t stream) {
  const float* q  = (const float*)d_in[0];
  const float* kv = (const float*)d_in[1];
  const float* Wq = (const float*)d_in[2];
  const float* bq = (const float*)d_in[3];
  const float* Wk = (const float*)d_in[4];
  const float* bk = (const float*)d_in[5];
  const float* Wv = (const float*)d_in[6];
  const float* bv = (const float*)d_in[7];
  const float* Wo = (const float*)d_in[8];
  const float* bo = (const float*)d_in[9];

  const size_t MB = 1u << 20;
  char* ws = (char*)d_ws;
  u16* qb  = (u16*)(ws + 0 * MB);    // 8 MB   bf16(q)   [8192][512]
  u16* kvb = (u16*)(ws + 8 * MB);    // 8 MB   bf16(kv)
  u16* wqb = (u16*)(ws + 16 * MB);   // 0.5 MB
  u16* wkb = (u16*)(ws + 16 * MB + 524288);
  u16* wvb = (u16*)(ws + 17 * MB);
  u16* wob = (u16*)(ws + 17 * MB + 524288);
  u16* Qh  = (u16*)(ws + 18 * MB);   // 8 MB   [16][4096][64]
  u16* Kh  = (u16*)(ws + 26 * MB);   // 8 MB   [16][4096][64]
  u16* Vt  = (u16*)(ws + 34 * MB);   // 8 MB   [16][64][4096]
  u16* aO  = (u16*)(ws + 42 * MB);   // 8 MB   [8192][512]

  // conversions
  cvt_bf16_kernel<<<dim3(4096), dim3(256), 0, stream>>>(q, qb, 1048576);
  cvt_bf16_kernel<<<dim3(4096), dim3(256), 0, stream>>>(kv, kvb, 1048576);
  cvt_bf16_kernel<<<dim3(256), dim3(256), 0, stream>>>(Wq, wqb, 65536);
  cvt_bf16_kernel<<<dim3(256), dim3(256), 0, stream>>>(Wk, wkb, 65536);
  cvt_bf16_kernel<<<dim3(256), dim3(256), 0, stream>>>(Wv, wvb, 65536);
  cvt_bf16_kernel<<<dim3(256), dim3(256), 0, stream>>>(Wo, wob, 65536);

  // projections
  gemm_bt<0><<<dim3(64, 4), dim3(256), 0, stream>>>(qb,  wqb, bq, (void*)Qh);
  gemm_bt<0><<<dim3(64, 4), dim3(256), 0, stream>>>(kvb, wkb, bk, (void*)Kh);
  gemm_bt<1><<<dim3(64, 4), dim3(256), 0, stream>>>(kvb, wvb, bv, (void*)Vt);

  // attention
  attn_kernel<<<dim3(512), dim3(256), 0, stream>>>(Qh, Kh, Vt, aO);

  // output projection (f32 out)
  gemm_bt<2><<<dim3(64, 4), dim3(256), 0, stream>>>(aO, wob, bo, d_out);
}

// Round 2
// 187.568 us; speedup vs baseline: 1.6390x; 1.6390x over previous
//
#include <hip/hip_runtime.h>
#include <stdint.h>

typedef unsigned short u16;
typedef __attribute__((ext_vector_type(8))) short short8;
typedef __attribute__((ext_vector_type(4))) float f32x4;
typedef __attribute__((ext_vector_type(16))) float f32x16;

typedef __attribute__((address_space(1))) void as1_void;
typedef __attribute__((address_space(3))) void as3_void;

__device__ inline u16 f2bf(float x) {
  uint32_t u = __float_as_uint(x);
  return (u16)((u + 0x7fffu + ((u >> 16) & 1u)) >> 16);
}

__device__ inline void gload16(const void* g, void* l) {
  __builtin_amdgcn_global_load_lds((as1_void*)g, (as3_void*)l, 16, 0, 0);
}

__device__ inline uint32_t cvtpk(float lo, float hi) {
  uint32_t d;
  asm("v_cvt_pk_bf16_f32 %0, %1, %2" : "=v"(d) : "v"(lo), "v"(hi));
  return d;
}

__device__ inline void plswap(uint32_t& a, uint32_t& b) {
  asm("v_permlane32_swap_b32 %0, %1" : "+v"(a), "+v"(b));
}

__device__ inline float fexp2(float x) {
  float r;
  asm("v_exp_f32 %0, %1" : "=v"(r) : "v"(x));
  return r;
}

// ---------------- f32 -> bf16 conversion (vectorized) ----------------
__global__ __launch_bounds__(256) void cvt_bf16_kernel(const float* __restrict__ in,
                                                       u16* __restrict__ out, int n4) {
  int i = blockIdx.x * 256 + threadIdx.x;
  if (i >= n4) return;
  float4 v = ((const float4*)in)[i];
  ushort4 o;
  o.x = f2bf(v.x); o.y = f2bf(v.y); o.z = f2bf(v.z); o.w = f2bf(v.w);
  ((ushort4*)out)[i] = o;
}

// ---------------- GEMM: C[m,n] = (sum_k A[m,k]*W[n,k] + bias[n]) * prescale ----
// M=8192, N=512, K=512. Tile 128x128, 4 waves (2x2), BK=32.
// MODE 0: bf16 out at [(b*8+h)*4096+s]*64+d   (Q/K head layout)
// MODE 1: bf16 out at [(b*8+h)*64+d]*4096+s   (V transposed)
// MODE 2: f32  out at m*512+n                  (final projection)
template <int MODE>
__global__ __launch_bounds__(256) void gemm_bt(const u16* __restrict__ A,
                                               const u16* __restrict__ W,
                                               const float* __restrict__ bias,
                                               void* __restrict__ Cout, float prescale) {
  __shared__ u16 Al[128 * 32];
  __shared__ u16 Wl[128 * 32];
  const int tid = threadIdx.x;
  const int lane = tid & 63;
  const int wv = tid >> 6;
  const int c = lane & 15;
  const int g = lane >> 4;
  const int wr = wv >> 1, wc = wv & 1;
  const int m0 = blockIdx.x * 128;
  const int n0 = blockIdx.y * 128;

  f32x4 acc[4][4];
#pragma unroll
  for (int i = 0; i < 4; i++)
#pragma unroll
    for (int j = 0; j < 4; j++) acc[i][j] = (f32x4){0.f, 0.f, 0.f, 0.f};

  for (int kk = 0; kk < 512; kk += 32) {
    __syncthreads();
    {
      int t0 = tid;
      int r0 = t0 >> 2, c0 = t0 & 3;
      gload16(A + (size_t)(m0 + r0) * 512 + kk + c0 * 8, (char*)Al + (size_t)(wv * 64) * 16);
      gload16(W + (size_t)(n0 + r0) * 512 + kk + c0 * 8, (char*)Wl + (size_t)(wv * 64) * 16);
      int t1 = 256 + tid;
      int r1 = t1 >> 2, c1 = t1 & 3;
      gload16(A + (size_t)(m0 + r1) * 512 + kk + c1 * 8, (char*)Al + (size_t)(256 + wv * 64) * 16);
      gload16(W + (size_t)(n0 + r1) * 512 + kk + c1 * 8, (char*)Wl + (size_t)(256 + wv * 64) * 16);
    }
    __syncthreads();

    short8 af[4], wf[4];
#pragma unroll
    for (int ai = 0; ai < 4; ai++)
      af[ai] = *(const short8*)&Al[(wr * 64 + ai * 16 + c) * 32 + g * 8];
#pragma unroll
    for (int bj = 0; bj < 4; bj++)
      wf[bj] = *(const short8*)&Wl[(wc * 64 + bj * 16 + c) * 32 + g * 8];
#pragma unroll
    for (int ai = 0; ai < 4; ai++)
#pragma unroll
      for (int bj = 0; bj < 4; bj++)
        acc[ai][bj] = __builtin_amdgcn_mfma_f32_16x16x32_bf16(af[ai], wf[bj], acc[ai][bj], 0, 0, 0);
  }

#pragma unroll
  for (int ai = 0; ai < 4; ai++)
#pragma unroll
    for (int bj = 0; bj < 4; bj++)
#pragma unroll
      for (int r = 0; r < 4; r++) {
        int m = m0 + wr * 64 + ai * 16 + g * 4 + r;
        int n = n0 + wc * 64 + bj * 16 + c;
        float v = (acc[ai][bj][r] + bias[n]) * prescale;
        if (MODE == 2) {
          ((float*)Cout)[(size_t)m * 512 + n] = v;
        } else {
          int b = m >> 12, s = m & 4095;
          int h = n >> 6, d = n & 63;
          size_t idx;
          if (MODE == 0)
            idx = ((size_t)(b * 8 + h) * 4096 + s) * 64 + d;
          else
            idx = ((size_t)(b * 8 + h) * 64 + d) * 4096 + s;
          ((u16*)Cout)[idx] = f2bf(v);
        }
      }
}

// ---------------- Flash attention, 32x32 swapped structure ----------------
// Grid: 16 bh * 32 qtiles (512 blocks). 4 waves x 32 q-rows = 128 q/block.
// KV tile 64. K in LDS [32][128] swizzled (K[kv][d] at row kv&31, 16B-block
// ((kv>>5)*8 + d/8) ^ (kv&15)); V^T likewise (rows d&31).
// S^T = mfma(K,Q): lane holds 32 scores of q-row (lane&31) -> in-reg softmax.
// P^T -> B-frag via cvt_pk_bf16 + permlane32_swap. O^T = mfma(V^T, P^T):
// accumulator col = q-row -> lane-local rescale/normalize.
__global__ __launch_bounds__(256) void attn_kernel(const u16* __restrict__ Qh,
                                                   const u16* __restrict__ Kh,
                                                   const u16* __restrict__ Vt,
                                                   u16* __restrict__ Oa) {
  __shared__ u16 Kl[32 * 128];
  __shared__ u16 Vl[32 * 128];
  const int tid = threadIdx.x;
  const int lane = tid & 63;
  const int w = tid >> 6;
  const int c5 = lane & 31;
  const int h = lane >> 5;
  const int bh = blockIdx.x >> 5;
  const int qt = blockIdx.x & 31;
  const int q0 = qt * 128 + w * 32;
  const u16* Qb = Qh + (size_t)bh * 4096 * 64;
  const u16* Kb = Kh + (size_t)bh * 4096 * 64;
  const u16* Vb = Vt + (size_t)bh * 64 * 4096;

  // Q B-frag: lane (c5,h) holds Q[q0+c5][16*kd + 8*h + j], pre-scaled by log2e/8
  short8 qf[4];
#pragma unroll
  for (int kd = 0; kd < 4; kd++)
    qf[kd] = *(const short8*)(Qb + (size_t)(q0 + c5) * 64 + kd * 16 + h * 8);

  f32x16 accO[2];
#pragma unroll
  for (int i = 0; i < 16; i++) { accO[0][i] = 0.f; accO[1][i] = 0.f; }
  float m_r = -1e30f, l_r = 0.f;

  // staging: each thread stages 2 K chunks + 2 V chunks of 16B
  const int rA = tid >> 3, e8 = tid & 7;
  const int dstK = rA * 128 + ((e8 ^ (rA & 15)) << 3);  // u16 index; chunk1 = ^64
  const size_t srcK0 = (size_t)rA * 64 + e8 * 8, srcK1 = srcK0 + 32 * 64;
  const int dstV = dstK;
  const size_t srcV0 = (size_t)rA * 4096 + e8 * 8, srcV1 = srcV0 + (size_t)32 * 4096;

  int4 k0 = *(const int4*)(Kb + srcK0);
  int4 k1 = *(const int4*)(Kb + srcK1);
  int4 v0 = *(const int4*)(Vb + srcV0);
  int4 v1 = *(const int4*)(Vb + srcV1);

  const int swz = c5 & 15;
  const int rowb = c5 * 128;

  for (int kv0 = 0; kv0 < 4096; kv0 += 64) {
    __syncthreads();
    *(int4*)&Kl[dstK] = k0; *(int4*)&Kl[dstK ^ 64] = k1;
    *(int4*)&Vl[dstV] = v0; *(int4*)&Vl[dstV ^ 64] = v1;
    __syncthreads();
    if (kv0 + 64 < 4096) {  // prefetch next tile into regs; hides under compute
      const u16* Kn = Kb + (size_t)(kv0 + 64) * 64;
      const u16* Vn = Vb + (kv0 + 64);
      k0 = *(const int4*)(Kn + srcK0); k1 = *(const int4*)(Kn + srcK1);
      v0 = *(const int4*)(Vn + srcV0); v1 = *(const int4*)(Vn + srcV1);
    }

    // S^T = K * Q^T : s{kb} lane(c5,h): q=c5, kv = 32*kb + 4h + (r&3) + 8*(r>>2)
    f32x16 s0, s1;
#pragma unroll
    for (int i = 0; i < 16; i++) { s0[i] = 0.f; s1[i] = 0.f; }
#pragma unroll
    for (int kd = 0; kd < 4; kd++) {
      short8 kf0 = *(const short8*)&Kl[rowb + ((((kd << 1) + h) ^ swz) << 3)];
      short8 kf1 = *(const short8*)&Kl[rowb + (((8 + (kd << 1) + h) ^ swz) << 3)];
      s0 = __builtin_amdgcn_mfma_f32_32x32x16_bf16(kf0, qf[kd], s0, 0, 0, 0);
      s1 = __builtin_amdgcn_mfma_f32_32x32x16_bf16(kf1, qf[kd], s1, 0, 0, 0);
    }

    // in-register online softmax (scores already in log2 domain)
    float t[16];
#pragma unroll
    for (int i = 0; i < 16; i++) t[i] = fmaxf(s0[i], s1[i]);
#pragma unroll
    for (int st = 8; st > 0; st >>= 1)
#pragma unroll
      for (int i = 0; i < 16; i++) if (i < st) t[i] = fmaxf(t[i], t[i + st]);
    float tm = fmaxf(t[0], __shfl_xor(t[0], 32));
    float mn = fmaxf(m_r, tm);
    float corr = fexp2(m_r - mn);
#pragma unroll
    for (int i = 0; i < 16; i++) { s0[i] = fexp2(s0[i] - mn); s1[i] = fexp2(s1[i] - mn); }
#pragma unroll
    for (int i = 0; i < 16; i++) t[i] = s0[i] + s1[i];
#pragma unroll
    for (int st = 8; st > 0; st >>= 1)
#pragma unroll
      for (int i = 0; i < 16; i++) if (i < st) t[i] += t[i + st];
    float rs = t[0] + __shfl_xor(t[0], 32);
    l_r = l_r * corr + rs;
    m_r = mn;
#pragma unroll
    for (int i = 0; i < 16; i++) { accO[0][i] *= corr; accO[1][i] *= corr; }

    // P -> bf16 A/B-frag in-register: pk{kb}[u] = {cvtpk(p[4u],p[4u+1]), cvtpk(p[4u+2],p[4u+3])}
    uint32_t pk0[4][2], pk1[4][2];
#pragma unroll
    for (int u = 0; u < 4; u++) {
      pk0[u][0] = cvtpk(s0[4 * u], s0[4 * u + 1]);
      pk0[u][1] = cvtpk(s0[4 * u + 2], s0[4 * u + 3]);
      pk1[u][0] = cvtpk(s1[4 * u], s1[4 * u + 1]);
      pk1[u][1] = cvtpk(s1[4 * u + 2], s1[4 * u + 3]);
    }
    // pa[km]: lane (c5,h) holds P[q=c5][kv = 16*km + 8h + j]
    short8 pa[4];
#pragma unroll
    for (int km = 0; km < 2; km++) {
      const int uA = (km & 1) * 2, uB = uA + 1;
      uint32_t a0 = pk0[uA][0], b0 = pk0[uB][0]; plswap(a0, b0);
      uint32_t a1 = pk0[uA][1], b1 = pk0[uB][1]; plswap(a1, b1);
      union { uint32_t u[4]; short8 s; } uu;
      uu.u[0] = a0; uu.u[1] = a1; uu.u[2] = b0; uu.u[3] = b1;
      pa[km] = uu.s;
    }
#pragma unroll
    for (int km = 2; km < 4; km++) {
      const int uA = (km & 1) * 2, uB = uA + 1;
      uint32_t a0 = pk1[uA][0], b0 = pk1[uB][0]; plswap(a0, b0);
      uint32_t a1 = pk1[uA][1], b1 = pk1[uB][1]; plswap(a1, b1);
      union { uint32_t u[4]; short8 s; } uu;
      uu.u[0] = a0; uu.u[1] = a1; uu.u[2] = b0; uu.u[3] = b1;
      pa[km] = uu.s;
    }

    // O^T += V^T * P^T : accO[db] lane(c5,h): q=c5, d = 32*db + 4h + (r&3) + 8*(r>>2)
#pragma unroll
    for (int km = 0; km < 4; km++) {
      short8 vf0 = *(const short8*)&Vl[rowb + ((((km << 1) + h) ^ swz) << 3)];
      short8 vf1 = *(const short8*)&Vl[rowb + (((8 + (km << 1) + h) ^ swz) << 3)];
      accO[0] = __builtin_amdgcn_mfma_f32_32x32x16_bf16(vf0, pa[km], accO[0], 0, 0, 0);
      accO[1] = __builtin_amdgcn_mfma_f32_32x32x16_bf16(vf1, pa[km], accO[1], 0, 0, 0);
    }
  }

  // epilogue: lane-local normalize, write [b][q][hh*64+d]
  const float inv = 1.f / l_r;
  const int b = bh >> 3, hh = bh & 7;
  const int qg = q0 + c5;
  u16* Ob = Oa + (size_t)(b * 4096 + qg) * 512 + hh * 64;
#pragma unroll
  for (int db = 0; db < 2; db++)
#pragma unroll
    for (int r = 0; r < 16; r++) {
      int d = db * 32 + 4 * h + (r & 3) + 8 * (r >> 2);
      Ob[d] = f2bf(accO[db][r] * inv);
    }
}

// ---------------- host launch ----------------
extern "C" void kernel_launch(void* const* d_in, const int* in_sizes, int n_in,
                              void* d_out, int out_size, void* d_ws, size_t ws_size,
                              hipStream_t stream) {
  const float* q  = (const float*)d_in[0];
  const float* kv = (const float*)d_in[1];
  const float* Wq = (const float*)d_in[2];
  const float* bq = (const float*)d_in[3];
  const float* Wk = (const float*)d_in[4];
  const float* bk = (const float*)d_in[5];
  const float* Wv = (const float*)d_in[6];
  const float* bv = (const float*)d_in[7];
  const float* Wo = (const float*)d_in[8];
  const float* bo = (const float*)d_in[9];

  const size_t MB = 1u << 20;
  char* ws = (char*)d_ws;
  u16* qb  = (u16*)(ws + 0 * MB);
  u16* kvb = (u16*)(ws + 8 * MB);
  u16* wqb = (u16*)(ws + 16 * MB);
  u16* wkb = (u16*)(ws + 16 * MB + 524288);
  u16* wvb = (u16*)(ws + 17 * MB);
  u16* wob = (u16*)(ws + 17 * MB + 524288);
  u16* Qh  = (u16*)(ws + 18 * MB);   // [16][4096][64], pre-scaled by log2e/8
  u16* Kh  = (u16*)(ws + 26 * MB);   // [16][4096][64]
  u16* Vt  = (u16*)(ws + 34 * MB);   // [16][64][4096]
  u16* aO  = (u16*)(ws + 42 * MB);   // [8192][512]

  cvt_bf16_kernel<<<dim3(4096), dim3(256), 0, stream>>>(q, qb, 1048576);
  cvt_bf16_kernel<<<dim3(4096), dim3(256), 0, stream>>>(kv, kvb, 1048576);
  cvt_bf16_kernel<<<dim3(256), dim3(256), 0, stream>>>(Wq, wqb, 65536);
  cvt_bf16_kernel<<<dim3(256), dim3(256), 0, stream>>>(Wk, wkb, 65536);
  cvt_bf16_kernel<<<dim3(256), dim3(256), 0, stream>>>(Wv, wvb, 65536);
  cvt_bf16_kernel<<<dim3(256), dim3(256), 0, stream>>>(Wo, wob, 65536);

  const float qscale = 0.125f * 1.44269504088896340736f;  // (1/sqrt(64)) * log2(e)
  gemm_bt<0><<<dim3(64, 4), dim3(256), 0, stream>>>(qb,  wqb, bq, (void*)Qh, qscale);
  gemm_bt<0><<<dim3(64, 4), dim3(256), 0, stream>>>(kvb, wkb, bk, (void*)Kh, 1.0f);
  gemm_bt<1><<<dim3(64, 4), dim3(256), 0, stream>>>(kvb, wvb, bv, (void*)Vt, 1.0f);

  attn_kernel<<<dim3(512), dim3(256), 0, stream>>>(Qh, Kh, Vt, aO);

  gemm_bt<2><<<dim3(64, 4), dim3(256), 0, stream>>>(aO, wob, bo, d_out, 1.0f);
}